// Round 1
// baseline (6930.424 us; speedup 1.0000x reference)
//
#include <hip/hip_runtime.h>
#include <math.h>

#define N 1024
#define NN (N*N)

// ======================= init =======================
__global__ void init_kernel(double* scores) {
  int t = threadIdx.x;
  if (t < 16) scores[t] = 0.0;
}

// ======================= copy x -> LU workspace =======================
__global__ __launch_bounds__(256) void copy_kernel(const float4* __restrict__ src,
                                                   float4* __restrict__ dst) {
  int i = blockIdx.x * 256 + threadIdx.x;   // grid sized exactly: 16M floats / 4
  dst[i] = src[i];
}

// ======================= LU panel (width 32): REGISTER-RESIDENT rows =============
// 256 threads / 4 waves per matrix. Each thread holds rows tid, tid+256, tid+512,
// tid+768 entirely in registers (float4 row[4][8] = 128 VGPR). NO physical row
// swaps: pivoting tracked via virtual<->physical permutation maps (Vv/Pv, thread 0),
// pivot row broadcast through a 32-float LDS buffer. Per step the only LDS traffic
// is the broadcast + 8B reduction state (vs ~64KB/step round-trips before).
// Emits rowsrc[i] = physical row holding virtual row i (consumed by ptrsm/update
// instead of LAPACK swap-format ipiv). Pivot choice = argmax |col j| over active
// rows, tie -> min physical row (tie-break order differs from LAPACK's swapped
// frame only on exact fp ties: measure-zero on this data; log|det| unaffected by
// row order otherwise). 2 barriers/step, both cheap.
__global__ __launch_bounds__(256, 1) void panel_kernel(float* __restrict__ lu,
                                                       unsigned short* __restrict__ rowsrc,
                                                       double* __restrict__ scores,
                                                       int c0) {
  __shared__ __align__(16) float prow[32];   // pivot row broadcast buffer
  __shared__ float ujjS[32];
  __shared__ float redv[2][4];               // parity-buffered cross-wave reduce
  __shared__ int   redk[2][4];
  __shared__ int Vv[1024];                   // virtual -> physical (rel c0)
  __shared__ int Pv[1024];                   // physical -> virtual
  const int m = blockIdx.x;
  float* A = lu + (size_t)m * NN;
  const int R = N - c0;
  const int tid = threadIdx.x;

  // ---- load owned rows into registers (cols c0..c0+31; c0 % 32 == 0) ----
  float4 row[4][8] = {};
  unsigned actm = 0u;
  #pragma unroll
  for (int k = 0; k < 4; ++k) {
    int r = tid + (k << 8);
    if (r < R) {
      actm |= (1u << k);
      const float* src = A + (size_t)(c0 + r) * N + c0;
      #pragma unroll
      for (int q = 0; q < 8; ++q) row[k][q] = *(const float4*)(src + 4 * q);
    }
  }
  for (int i = tid; i < R; i += 256) { Vv[i] = i; Pv[i] = i; }

  // ---- prescan: pivot for column 0 ----
  {
    float bval = -1.0f; int brow = 0x7fffffff;
    #pragma unroll
    for (int k = 0; k < 4; ++k) {
      if ((actm >> k) & 1u) {
        int r = tid + (k << 8);
        float v = fabsf(row[k][0].x);
        if (v > bval || (v == bval && r < brow)) { bval = v; brow = r; }
      }
    }
    #pragma unroll
    for (int mask = 32; mask; mask >>= 1) {
      float ov = __shfl_xor(bval, mask);
      int   orr = __shfl_xor(brow, mask);
      if (ov > bval || (ov == bval && orr < brow)) { bval = ov; brow = orr; }
    }
    if ((tid & 63) == 0) { redv[0][tid >> 6] = bval; redk[0][tid >> 6] = brow; }
  }
  __syncthreads();   // redv[0] + Vv/Pv init visible

  #pragma unroll 1
  for (int j = 0; j < 32; ++j) {
    // ---- combine 4-wave partials -> physical pivot row pcur (redundant, all) ----
    int pcur;
    {
      const int pb = j & 1;
      float bv = redv[pb][0]; int bk = redk[pb][0];
      float v1 = redv[pb][1]; int k1 = redk[pb][1];
      float v2 = redv[pb][2]; int k2 = redk[pb][2];
      float v3 = redv[pb][3]; int k3 = redk[pb][3];
      if (v1 > bv || (v1 == bv && k1 < bk)) { bv = v1; bk = k1; }
      if (v2 > bv || (v2 == bv && k2 < bk)) { bv = v2; bk = k2; }
      if (v3 > bv || (v3 == bv && k3 < bk)) { bv = v3; bk = k3; }
      pcur = bk;
    }
    // ---- owner publishes pivot row from registers; retires it ----
    if (tid == (pcur & 255)) {
      const int kk = pcur >> 8;
      float4* pd = (float4*)prow;
      #pragma unroll
      for (int q = 0; q < 8; ++q) {
        float4 v = row[0][q];           // static-index select chain (stays in VGPRs)
        if (kk == 1) v = row[1][q];
        if (kk == 2) v = row[2][q];
        if (kk == 3) v = row[3][q];
        pd[q] = v;
      }
      actm &= ~(1u << kk);
    }
    // ---- thread 0: maintain virtual<->physical permutation ----
    if (tid == 0) {
      int b  = Pv[pcur];                // virtual index of pivot (>= j)
      int pa = Vv[j];
      Vv[j] = pcur; Vv[b] = pa;
      Pv[pcur] = j; Pv[pa] = b;
    }
    __syncthreads();   // B1: prow visible

    const float ujj = prow[j];
    if (tid == 0) ujjS[j] = ujj;
    const float rujj = 1.0f / ujj;
    const int qj = j >> 2, ej = j & 3;
    const int jn = j + 1;
    const int qn = (j < 31) ? (jn >> 2) : -1, en = jn & 3;

    // U-row chunks -> static registers (broadcast b128 reads)
    float4 u4[8];
    #pragma unroll
    for (int q = 0; q < 8; ++q)
      if (4 * q + 3 >= j) u4[q] = *(const float4*)&prow[4 * q];

    // ---- update owned active rows in registers; fused scan of column j+1 ----
    float bval = -1.0f; int brow = 0x7fffffff;
    #pragma unroll
    for (int k = 0; k < 4; ++k) {
      if ((actm >> k) & 1u) {
        const int r = tid + (k << 8);
        float l = 0.0f, nv = 0.0f;
        #pragma unroll
        for (int q = 0; q < 8; ++q) {
          if (q < qj) continue;                  // uniform runtime guard
          float4 v = row[k][q];
          if (q == qj) {
            float aj = (ej == 0) ? v.x : (ej == 1) ? v.y : (ej == 2) ? v.z : v.w;
            l = aj * rujj;
            if (ej == 0)      { v.x = l; v.y -= l * u4[q].y; v.z -= l * u4[q].z; v.w -= l * u4[q].w; }
            else if (ej == 1) { v.y = l; v.z -= l * u4[q].z; v.w -= l * u4[q].w; }
            else if (ej == 2) { v.z = l; v.w -= l * u4[q].w; }
            else              { v.w = l; }
          } else {
            v.x -= l * u4[q].x; v.y -= l * u4[q].y;
            v.z -= l * u4[q].z; v.w -= l * u4[q].w;
          }
          if (q == qn)
            nv = (en == 0) ? v.x : (en == 1) ? v.y : (en == 2) ? v.z : v.w;
          row[k][q] = v;
        }
        if (j < 31) {
          float av = fabsf(nv);
          if (av > bval || (av == bval && r < brow)) { bval = av; brow = r; }
        }
      }
    }
    if (j < 31) {
      #pragma unroll
      for (int mask = 32; mask; mask >>= 1) {
        float ov = __shfl_xor(bval, mask);
        int   orr = __shfl_xor(brow, mask);
        if (ov > bval || (ov == bval && orr < brow)) { bval = ov; brow = orr; }
      }
      if ((tid & 63) == 0) { redv[jn & 1][tid >> 6] = bval; redk[jn & 1][tid >> 6] = brow; }
    }
    __syncthreads();   // B2: updates done reading prow; redv visible for next step
  }

  // ---- writeback (all rows, original slots: panel cols stay aligned w/ source) ----
  #pragma unroll
  for (int k = 0; k < 4; ++k) {
    int r = tid + (k << 8);
    if (r < R) {
      float* dst = A + (size_t)(c0 + r) * N + c0;
      #pragma unroll
      for (int q = 0; q < 8; ++q) *(float4*)(dst + 4 * q) = row[k][q];
    }
  }
  // ---- emit permutation: rowsrc[i] = physical row (abs) holding virtual row i ----
  for (int i = tid; i < R; i += 256) rowsrc[m * 1024 + i] = (unsigned short)(c0 + Vv[i]);
  // ---- logsum: lane-parallel logs + shfl-reduce (wave 0) ----
  if (tid < 64) {
    double lg = 0.0;
    if (tid < 32) lg = log(fabs((double)ujjS[tid]));
    #pragma unroll
    for (int mask = 32; mask; mask >>= 1) lg += __shfl_xor(lg, mask);
    if (tid == 0) atomicAdd(&scores[m], lg);
  }
}

// ======================= permutation-gather + TRSM =======================
// rowAt loaded directly from panel's rowsrc (no swap simulation). L11 rows read
// through rowAt (panel writes factors back to ORIGINAL slots now). Trailing-col
// consolidation unchanged; panel cols are never consolidated (update reads L21
// through rowsrc indirection; panel cols are dead afterwards).
__global__ __launch_bounds__(256) void ptrsm_kernel(float* __restrict__ lu,
                                                    const unsigned short* __restrict__ rowsrc,
                                                    int c0, int ncs) {
  const int m  = blockIdx.x / ncs;
  const int cs = blockIdx.x % ncs;
  const int s0 = c0 + 32 + cs * 256;
  const int tid = threadIdx.x;
  const int col = s0 + tid;
  const bool ac = col < N;
  float* A = lu + (size_t)m * NN;
  const int R = N - c0;
  __shared__ int   rowAt[1024];     // content map over rows [c0, N)
  __shared__ float L11s[32][33];
  __shared__ int   dDst[48];
  __shared__ int   dSrc[48];
  __shared__ int   dcount;

  for (int r = tid; r < R; r += 256) rowAt[r] = (int)rowsrc[m * 1024 + r];
  if (tid == 0) dcount = 0;
  __syncthreads();
  for (int idx = tid; idx < 1024; idx += 256) {
    int i = idx >> 5, k = idx & 31;
    L11s[i][k] = A[(size_t)rowAt[i] * N + c0 + k];
  }
  // collect displaced A22 rows (dst receives content of src)
  for (int r = 32 + tid; r < R; r += 256) {
    if (rowAt[r] != c0 + r) {
      int i = atomicAdd(&dcount, 1);
      dDst[i] = c0 + r; dSrc[i] = rowAt[r];
    }
  }
  __syncthreads();
  const int nd = dcount;   // <= 32

  // ---- read phase (all loads before any store) ----
  float pay[32];
  #pragma unroll
  for (int i = 0; i < 32; ++i)
    if (i < nd && ac) pay[i] = A[(size_t)dSrc[i] * N + col];
  float u[32];
  #pragma unroll
  for (int i = 0; i < 32; ++i)
    if (ac) u[i] = A[(size_t)rowAt[i] * N + col];

  // ---- TRSM: u = L11^{-1} a12 (unit diag) ----
  #pragma unroll
  for (int i = 1; i < 32; ++i) {
    float a = u[i];
    #pragma unroll
    for (int k = 0; k < 32; ++k)
      if (k < i) a -= L11s[i][k] * u[k];
    u[i] = a;
  }

  // ---- write phase ----
  #pragma unroll
  for (int i = 0; i < 32; ++i)
    if (i < nd && ac) A[(size_t)dDst[i] * N + col] = pay[i];
  #pragma unroll
  for (int i = 0; i < 32; ++i)
    if (ac) A[(size_t)(c0 + i) * N + col] = u[i];
}

// ======================= trailing update: A22 -= L21 @ U12 (K=32) ================
// L21 multipliers read through rowsrc indirection (they stay at original slots).
__global__ __launch_bounds__(256) void update_kernel(float* __restrict__ lu,
                                                     const unsigned short* __restrict__ rowsrc,
                                                     int c0, int nrt, int ncs) {
  const int per = nrt * ncs;
  const int m  = blockIdx.x / per;
  const int t  = blockIdx.x % per;
  const int rt = t / ncs, cs = t % ncs;
  const int r0 = c0 + 32 + rt * 64;
  const int s0 = c0 + 32 + cs * 256;
  const int tid = threadIdx.x;
  float* A = lu + (size_t)m * NN;
  __shared__ float Lts[32][68];    // L21 tile transposed: [k][r]
  __shared__ float Us[32][260];    // U12 stripe: [k][c]
  for (int idx = tid; idx < 2048; idx += 256) {
    int r = idx >> 5, k = idx & 31;
    int rr = r0 + r;
    Lts[k][r] = (rr < N) ? A[(size_t)rowsrc[m * 1024 + rr - c0] * N + c0 + k] : 0.0f;
  }
  for (int idx = tid; idx < 8192; idx += 256) {
    int k = idx >> 8, c = idx & 255;
    Us[k][c] = (s0 + c < N) ? A[(size_t)(c0 + k) * N + s0 + c] : 0.0f;
  }
  __syncthreads();
  const int tx = tid & 63;    // col group: 4 cols
  const int ty = tid >> 6;    // row group: 16 rows (== wave id -> uniform a-reads)
  float4 acc[16];
  #pragma unroll
  for (int e = 0; e < 16; ++e) acc[e] = make_float4(0.f, 0.f, 0.f, 0.f);
  #pragma unroll 4
  for (int k = 0; k < 32; ++k) {
    float4 b  = *(const float4*)&Us[k][tx * 4];
    float4 a0 = *(const float4*)&Lts[k][ty * 16 + 0];
    float4 a1 = *(const float4*)&Lts[k][ty * 16 + 4];
    float4 a2 = *(const float4*)&Lts[k][ty * 16 + 8];
    float4 a3 = *(const float4*)&Lts[k][ty * 16 + 12];
    acc[0].x  += a0.x*b.x; acc[0].y  += a0.x*b.y; acc[0].z  += a0.x*b.z; acc[0].w  += a0.x*b.w;
    acc[1].x  += a0.y*b.x; acc[1].y  += a0.y*b.y; acc[1].z  += a0.y*b.z; acc[1].w  += a0.y*b.w;
    acc[2].x  += a0.z*b.x; acc[2].y  += a0.z*b.y; acc[2].z  += a0.z*b.z; acc[2].w  += a0.z*b.w;
    acc[3].x  += a0.w*b.x; acc[3].y  += a0.w*b.y; acc[3].z  += a0.w*b.z; acc[3].w  += a0.w*b.w;
    acc[4].x  += a1.x*b.x; acc[4].y  += a1.x*b.y; acc[4].z  += a1.x*b.z; acc[4].w  += a1.x*b.w;
    acc[5].x  += a1.y*b.x; acc[5].y  += a1.y*b.y; acc[5].z  += a1.y*b.z; acc[5].w  += a1.y*b.w;
    acc[6].x  += a1.z*b.x; acc[6].y  += a1.z*b.y; acc[6].z  += a1.z*b.z; acc[6].w  += a1.z*b.w;
    acc[7].x  += a1.w*b.x; acc[7].y  += a1.w*b.y; acc[7].z  += a1.w*b.z; acc[7].w  += a1.w*b.w;
    acc[8].x  += a2.x*b.x; acc[8].y  += a2.x*b.y; acc[8].z  += a2.x*b.z; acc[8].w  += a2.x*b.w;
    acc[9].x  += a2.y*b.x; acc[9].y  += a2.y*b.y; acc[9].z  += a2.y*b.z; acc[9].w  += a2.y*b.w;
    acc[10].x += a2.z*b.x; acc[10].y += a2.z*b.y; acc[10].z += a2.z*b.z; acc[10].w += a2.z*b.w;
    acc[11].x += a2.w*b.x; acc[11].y += a2.w*b.y; acc[11].z += a2.w*b.z; acc[11].w += a2.w*b.w;
    acc[12].x += a3.x*b.x; acc[12].y += a3.x*b.y; acc[12].z += a3.x*b.z; acc[12].w += a3.x*b.w;
    acc[13].x += a3.y*b.x; acc[13].y += a3.y*b.y; acc[13].z += a3.y*b.z; acc[13].w += a3.y*b.w;
    acc[14].x += a3.z*b.x; acc[14].y += a3.z*b.y; acc[14].z += a3.z*b.z; acc[14].w += a3.z*b.w;
    acc[15].x += a3.w*b.x; acc[15].y += a3.w*b.y; acc[15].z += a3.w*b.z; acc[15].w += a3.w*b.w;
  }
  const bool colok = (s0 + tx * 4) < N;
  #pragma unroll
  for (int e = 0; e < 16; ++e) {
    int r = r0 + ty * 16 + e;
    if (r < N && colok) {
      float4* p = (float4*)&A[(size_t)r * N + s0 + tx * 4];
      float4 v = *p;
      v.x -= acc[e].x; v.y -= acc[e].y; v.z -= acc[e].z; v.w -= acc[e].w;
      *p = v;
    }
  }
}

// ======================= gate + top-k + effective weights =======================
__global__ void select_kernel(const void* __restrict__ flagsraw, const double* __restrict__ scores,
                              const float* __restrict__ w1, const float* __restrict__ b1,
                              const float* __restrict__ w2, const float* __restrict__ b2,
                              int* __restrict__ topidx, float* __restrict__ misc,
                              float* __restrict__ out_tail) {
  if (threadIdx.x != 0 || blockIdx.x != 0) return;
  const unsigned char* fb = (const unsigned char*)flagsraw;
  bool nonbin = false, off4 = false;
  for (int i = 0; i < 16; ++i) {
    if (fb[i] > 1) nonbin = true;
    if ((i & 3) && fb[i]) off4 = true;
  }
  int f[16]; int nact = 0;
  for (int i = 0; i < 16; ++i) {
    int v;
    if (nonbin)      v = (((const float*)flagsraw)[i] != 0.0f);
    else if (off4)   v = (fb[i] != 0);
    else             v = (((const int*)flagsraw)[i] != 0);
    f[i] = v; nact += v;
  }
  int gate = (nact >= 4) ? 1 : 0;   // THRESH = 4
  double sc[16];
  for (int i = 0; i < 16; ++i) sc[i] = f[i] ? scores[i] : -1.0e300;
  bool used[16] = {};
  for (int k = 0; k < 8; ++k) {     // descending, ties -> lowest index (lax.top_k)
    int bi = -1; double bv = 0.0;
    for (int i = 0; i < 16; ++i)
      if (!used[i] && (bi < 0 || sc[i] > bv)) { bv = sc[i]; bi = i; }
    used[bi] = true;
    topidx[k] = bi;
  }
  for (int cC = 0; cC < 10; ++cC) {
    float s = 0.0f;
    for (int h = 0; h < 32; ++h) s += w2[h] * w1[h * 10 + cC];
    misc[cC] = s;
  }
  float be = 0.0f;
  for (int h = 0; h < 32; ++h) be += w2[h] * b1[h];
  be += b2[0];
  misc[10] = be;
  ((int*)misc)[12] = gate;
  *out_tail = gate ? 1.0f : 0.0f;
}

// ======================= build combined right-hand matrices M0..M2 =======================
__global__ __launch_bounds__(256) void build_m_kernel(const float* __restrict__ x,
                                                      const int* __restrict__ topidx,
                                                      const float* __restrict__ misc,
                                                      float* __restrict__ M) {
  int i = blockIdx.x * 256 + threadIdx.x;   // 262144 float4 positions
  const float4* T1 = (const float4*)(x + (size_t)topidx[1] * NN);
  const float4* T2 = (const float4*)(x + (size_t)topidx[2] * NN);
  const float4* T3 = (const float4*)(x + (size_t)topidx[3] * NN);
  float w0 = misc[0], w1_ = misc[1], w2_ = misc[2], w3_ = misc[3], w4_ = misc[4], w5_ = misc[5];
  float4 t1 = T1[i], t2 = T2[i], t3 = T3[i];
  float4 m0, m1, m2;
  m0.x = w0 * t1.x + w1_ * t2.x + w2_ * t3.x;
  m0.y = w0 * t1.y + w1_ * t2.y + w2_ * t3.y;
  m0.z = w0 * t1.z + w1_ * t2.z + w2_ * t3.z;
  m0.w = w0 * t1.w + w1_ * t2.w + w2_ * t3.w;
  m1.x = w3_ * t2.x + w4_ * t3.x;
  m1.y = w3_ * t2.y + w4_ * t3.y;
  m1.z = w3_ * t2.z + w4_ * t3.z;
  m1.w = w3_ * t2.w + w4_ * t3.w;
  m2.x = w5_ * t3.x;  m2.y = w5_ * t3.y;  m2.z = w5_ * t3.z;  m2.w = w5_ * t3.w;
  ((float4*)M)[i] = m0;
  ((float4*)(M + NN))[i] = m1;
  ((float4*)(M + 2 * (size_t)NN))[i] = m2;
}

// ======================= split-K final GEMM: P[chunk] = A_chunk @ B_chunk ==========
__global__ __launch_bounds__(256) void final_gemm_kernel(const float* __restrict__ x,
                                                         const float* __restrict__ M,
                                                         const int* __restrict__ topidx,
                                                         float* __restrict__ P) {
  const int chunk = blockIdx.x >> 8;   // 0..5
  const int t  = blockIdx.x & 255;
  const int tr = t >> 4, tc = t & 15;
  const int mi  = chunk >> 1;
  const int k0b = (chunk & 1) << 9;    // 0 or 512
  const float* A = x + (size_t)topidx[mi] * NN;
  const float* B = M + (size_t)mi * NN;
  __shared__ float As[32][68];   // A^T fragment: As[k][r], float4-aligned stride
  __shared__ float Bs[32][68];
  const int ty = threadIdx.x >> 4, tx = threadIdx.x & 15;
  float acc[4][4] = {};
  for (int k0 = k0b; k0 < k0b + 512; k0 += 32) {
    for (int idx = threadIdx.x; idx < 2048; idx += 256) {
      int r = idx >> 5, k = idx & 31;
      As[k][r] = A[(size_t)(tr * 64 + r) * N + k0 + k];
    }
    for (int idx = threadIdx.x; idx < 2048; idx += 256) {
      int k = idx >> 6, cc = idx & 63;
      Bs[k][cc] = B[(size_t)(k0 + k) * N + tc * 64 + cc];
    }
    __syncthreads();
    #pragma unroll 8
    for (int k = 0; k < 32; ++k) {
      float4 a = *(const float4*)&As[k][ty * 4];
      float4 b = *(const float4*)&Bs[k][tx * 4];
      acc[0][0] += a.x * b.x; acc[0][1] += a.x * b.y; acc[0][2] += a.x * b.z; acc[0][3] += a.x * b.w;
      acc[1][0] += a.y * b.x; acc[1][1] += a.y * b.y; acc[1][2] += a.y * b.z; acc[1][3] += a.y * b.w;
      acc[2][0] += a.z * b.x; acc[2][1] += a.z * b.y; acc[2][2] += a.z * b.z; acc[2][3] += a.z * b.w;
      acc[3][0] += a.w * b.x; acc[3][1] += a.w * b.y; acc[3][2] += a.w * b.z; acc[3][3] += a.w * b.w;
    }
    __syncthreads();
  }
  float* Pc = P + (size_t)chunk * NN;
  #pragma unroll
  for (int i = 0; i < 4; ++i) {
    size_t r = (size_t)(tr * 64 + ty * 4 + i);
    float4 v = make_float4(acc[i][0], acc[i][1], acc[i][2], acc[i][3]);
    *(float4*)&Pc[r * N + tc * 64 + tx * 4] = v;
  }
}

// ======================= reduce partials + preserve channels + bias ================
__global__ __launch_bounds__(256) void reduce_out_kernel(const float* __restrict__ x,
                                                         const float* __restrict__ P,
                                                         const int* __restrict__ topidx,
                                                         const float* __restrict__ misc,
                                                         float* __restrict__ out) {
  int i = blockIdx.x * 256 + threadIdx.x;   // 262144 float4 positions
  int gate = ((const int*)misc)[12];
  float4* o = (float4*)out;
  if (!gate) { o[i] = make_float4(0.f, 0.f, 0.f, 0.f); return; }
  float w6 = misc[6], w7 = misc[7], w8 = misc[8], w9 = misc[9], be = misc[10];
  float4 p0 = ((const float4*)(x + (size_t)topidx[4] * NN))[i];
  float4 p1 = ((const float4*)(x + (size_t)topidx[5] * NN))[i];
  float4 p2 = ((const float4*)(x + (size_t)topidx[6] * NN))[i];
  float4 p3 = ((const float4*)(x + (size_t)topidx[7] * NN))[i];
  float4 r;
  r.x = be + w6 * p0.x + w7 * p1.x + w8 * p2.x + w9 * p3.x;
  r.y = be + w6 * p0.y + w7 * p1.y + w8 * p2.y + w9 * p3.y;
  r.z = be + w6 * p0.z + w7 * p1.z + w8 * p2.z + w9 * p3.z;
  r.w = be + w6 * p0.w + w7 * p1.w + w8 * p2.w + w9 * p3.w;
  #pragma unroll
  for (int cN = 0; cN < 6; ++cN) {
    float4 q = ((const float4*)(P + (size_t)cN * NN))[i];
    r.x += q.x; r.y += q.y; r.z += q.z; r.w += q.w;
  }
  o[i] = r;
}

// ======================= host =======================
extern "C" void kernel_launch(void* const* d_in, const int* in_sizes, int n_in,
                              void* d_out, int out_size, void* d_ws, size_t ws_size,
                              hipStream_t stream) {
  const float* x  = (const float*)d_in[0];
  const void*  fl = d_in[1];
  const float* w1 = (const float*)d_in[2];
  const float* b1 = (const float*)d_in[3];
  const float* w2 = (const float*)d_in[4];
  const float* b2 = (const float*)d_in[5];
  float* out = (float*)d_out;

  char* ws = (char*)d_ws;
  float* LU = (float*)ws;                                // 64 MB (dead after LU phase)
  float* Mm = (float*)ws;                                // 12 MB, reuses LU space
  float* P  = (float*)(ws + (size_t)12 * 1024 * 1024);   // 24 MB partials, inside old LU
  size_t tail = (size_t)16 * NN * sizeof(float);         // 67,108,864
  double* scores = (double*)(ws + tail);                 // 16 doubles
  unsigned short* rowsrc = (unsigned short*)(ws + tail + 256);     // 16*1024 u16 = 32 KB
  int*    topidx = (int*)(ws + tail + 256 + 32768);      // 8 ints
  float*  misc   = (float*)(ws + tail + 256 + 32768 + 256); // weff[10], beff, gate

  init_kernel<<<1, 64, 0, stream>>>(scores);
  copy_kernel<<<16384, 256, 0, stream>>>((const float4*)x, (float4*)LU);

  for (int c0 = 0; c0 < N; c0 += 32) {
    panel_kernel<<<16, 256, 0, stream>>>(LU, rowsrc, scores, c0);
    int tcols = N - c0 - 32;
    if (tcols > 0) {
      int ncs = (tcols + 255) / 256;
      ptrsm_kernel<<<16 * ncs, 256, 0, stream>>>(LU, rowsrc, c0, ncs);
      int nrt = (tcols + 63) / 64;
      update_kernel<<<16 * nrt * ncs, 256, 0, stream>>>(LU, rowsrc, c0, nrt, ncs);
    }
  }

  select_kernel<<<1, 64, 0, stream>>>(fl, scores, w1, b1, w2, b2, topidx, misc, out + NN);
  build_m_kernel<<<1024, 256, 0, stream>>>(x, topidx, misc, Mm);
  final_gemm_kernel<<<1536, 256, 0, stream>>>(x, Mm, topidx, P);
  reduce_out_kernel<<<1024, 256, 0, stream>>>(x, P, topidx, misc, out);
}

// Round 2
// 4403.676 us; speedup vs baseline: 1.5738x; 1.5738x over previous
//
#include <hip/hip_runtime.h>
#include <math.h>

#define N 1024
#define NN (N*N)

// ======================= init =======================
__global__ void init_kernel(double* scores) {
  int t = threadIdx.x;
  if (t < 16) scores[t] = 0.0;
}

// ======================= copy x -> LU workspace =======================
__global__ __launch_bounds__(256) void copy_kernel(const float4* __restrict__ src,
                                                   float4* __restrict__ dst) {
  int i = blockIdx.x * 256 + threadIdx.x;   // grid sized exactly: 16M floats / 4
  dst[i] = src[i];
}

// ======================= LU panel (width 32): NAMED-REGISTER rows =============
// Round-1 post-mortem: float4 row[4][8] was scratch-allocated (VGPR_Count=36,
// 6.5MB HBM/dispatch, 240us). Fix: 32 NAMED float4 variables r{k}_{q} expanded
// via macros -> every access is a static SSA value, mem2reg must keep them in
// VGPRs. Algorithm identical to the verified round-1 kernel: no physical swaps,
// virtual<->physical permutation maps (thread 0), pivot row broadcast via 32-float
// LDS buffer, fused next-column scan, 2 barriers/step. Emits rowsrc[i] = physical
// row holding virtual row i.
__global__ __launch_bounds__(256, 1) void panel_kernel(float* __restrict__ lu,
                                                       unsigned short* __restrict__ rowsrc,
                                                       double* __restrict__ scores,
                                                       int c0) {
  __shared__ __align__(16) float prow[32];   // pivot row broadcast buffer
  __shared__ float ujjS[32];
  __shared__ float redv[2][4];               // parity-buffered cross-wave reduce
  __shared__ int   redk[2][4];
  __shared__ int Vv[1024];                   // virtual -> physical (rel c0)
  __shared__ int Pv[1024];                   // physical -> virtual
  const int m = blockIdx.x;
  float* A = lu + (size_t)m * NN;
  const int R = N - c0;
  const int tid = threadIdx.x;

  const float4 z4 = make_float4(0.f, 0.f, 0.f, 0.f);
  float4 r0_0=z4, r0_1=z4, r0_2=z4, r0_3=z4, r0_4=z4, r0_5=z4, r0_6=z4, r0_7=z4;
  float4 r1_0=z4, r1_1=z4, r1_2=z4, r1_3=z4, r1_4=z4, r1_5=z4, r1_6=z4, r1_7=z4;
  float4 r2_0=z4, r2_1=z4, r2_2=z4, r2_3=z4, r2_4=z4, r2_5=z4, r2_6=z4, r2_7=z4;
  float4 r3_0=z4, r3_1=z4, r3_2=z4, r3_3=z4, r3_4=z4, r3_5=z4, r3_6=z4, r3_7=z4;

  const bool ld0 = (tid           < R);
  const bool ld1 = (tid + 256     < R);
  const bool ld2 = (tid + 512     < R);
  const bool ld3 = (tid + 768     < R);
  bool act0 = ld0, act1 = ld1, act2 = ld2, act3 = ld3;

#define LOADK(K) \
  if (ld##K) { \
    const float* src_ = A + (size_t)(c0 + tid + (K << 8)) * N + c0; \
    r##K##_0 = *(const float4*)(src_ +  0); \
    r##K##_1 = *(const float4*)(src_ +  4); \
    r##K##_2 = *(const float4*)(src_ +  8); \
    r##K##_3 = *(const float4*)(src_ + 12); \
    r##K##_4 = *(const float4*)(src_ + 16); \
    r##K##_5 = *(const float4*)(src_ + 20); \
    r##K##_6 = *(const float4*)(src_ + 24); \
    r##K##_7 = *(const float4*)(src_ + 28); \
  }
  LOADK(0) LOADK(1) LOADK(2) LOADK(3)
#undef LOADK

  for (int i = tid; i < R; i += 256) { Vv[i] = i; Pv[i] = i; }

  // ---- prescan: pivot for column 0 ----
  {
    float bval = -1.0f; int brow = 0x7fffffff;
    if (act0) { float v = fabsf(r0_0.x); if (v > bval || (v == bval && tid       < brow)) { bval = v; brow = tid;       } }
    if (act1) { float v = fabsf(r1_0.x); if (v > bval || (v == bval && tid + 256 < brow)) { bval = v; brow = tid + 256; } }
    if (act2) { float v = fabsf(r2_0.x); if (v > bval || (v == bval && tid + 512 < brow)) { bval = v; brow = tid + 512; } }
    if (act3) { float v = fabsf(r3_0.x); if (v > bval || (v == bval && tid + 768 < brow)) { bval = v; brow = tid + 768; } }
    #pragma unroll
    for (int mask = 32; mask; mask >>= 1) {
      float ov = __shfl_xor(bval, mask);
      int   orr = __shfl_xor(brow, mask);
      if (ov > bval || (ov == bval && orr < brow)) { bval = ov; brow = orr; }
    }
    if ((tid & 63) == 0) { redv[0][tid >> 6] = bval; redk[0][tid >> 6] = brow; }
  }
  __syncthreads();   // redv[0] + Vv/Pv init visible

  #pragma unroll 1
  for (int j = 0; j < 32; ++j) {
    // ---- combine 4-wave partials -> physical pivot row pcur (redundant, all) ----
    int pcur;
    {
      const int pb = j & 1;
      float bv = redv[pb][0]; int bk = redk[pb][0];
      float v1 = redv[pb][1]; int k1 = redk[pb][1];
      float v2 = redv[pb][2]; int k2 = redk[pb][2];
      float v3 = redv[pb][3]; int k3 = redk[pb][3];
      if (v1 > bv || (v1 == bv && k1 < bk)) { bv = v1; bk = k1; }
      if (v2 > bv || (v2 == bv && k2 < bk)) { bv = v2; bk = k2; }
      if (v3 > bv || (v3 == bv && k3 < bk)) { bv = v3; bk = k3; }
      pcur = bk;
    }
    // ---- owner publishes pivot row from registers; retires it ----
    if (tid == (pcur & 255)) {
      const int kk = pcur >> 8;
      float4* pd = (float4*)prow;
#define PUBQ(Q) { \
      float4 v = r0_##Q; \
      if (kk == 1) v = r1_##Q; \
      if (kk == 2) v = r2_##Q; \
      if (kk == 3) v = r3_##Q; \
      pd[Q] = v; }
      PUBQ(0) PUBQ(1) PUBQ(2) PUBQ(3) PUBQ(4) PUBQ(5) PUBQ(6) PUBQ(7)
#undef PUBQ
      if (kk == 0) act0 = false;
      else if (kk == 1) act1 = false;
      else if (kk == 2) act2 = false;
      else act3 = false;
    }
    // ---- thread 0: maintain virtual<->physical permutation ----
    if (tid == 0) {
      int b  = Pv[pcur];                // virtual index of pivot (>= j)
      int pa = Vv[j];
      Vv[j] = pcur; Vv[b] = pa;
      Pv[pcur] = j; Pv[pa] = b;
    }
    __syncthreads();   // B1: prow visible

    const float ujj = prow[j];
    if (tid == 0) ujjS[j] = ujj;
    const float rujj = 1.0f / ujj;
    const int qj = j >> 2, ej = j & 3;
    const int jn = j + 1;
    const int qn = (j < 31) ? (jn >> 2) : -1, en = jn & 3;

    // U-row chunks -> static named registers (broadcast b128 reads)
    float4 u4_0=z4, u4_1=z4, u4_2=z4, u4_3=z4, u4_4=z4, u4_5=z4, u4_6=z4, u4_7=z4;
#define UREAD(Q) if (4 * Q + 3 >= j) u4_##Q = *(const float4*)&prow[4 * Q];
    UREAD(0) UREAD(1) UREAD(2) UREAD(3) UREAD(4) UREAD(5) UREAD(6) UREAD(7)
#undef UREAD

    // ---- update owned active rows in registers; fused scan of column j+1 ----
    float bval = -1.0f; int brow = 0x7fffffff;
#define QSTEP(K,Q) \
    if (Q >= qj) { \
      float4 v = r##K##_##Q; \
      if (Q == qj) { \
        float aj = (ej == 0) ? v.x : (ej == 1) ? v.y : (ej == 2) ? v.z : v.w; \
        l = aj * rujj; \
        if (ej == 0)      { v.x = l; v.y -= l * u4_##Q.y; v.z -= l * u4_##Q.z; v.w -= l * u4_##Q.w; } \
        else if (ej == 1) { v.y = l; v.z -= l * u4_##Q.z; v.w -= l * u4_##Q.w; } \
        else if (ej == 2) { v.z = l; v.w -= l * u4_##Q.w; } \
        else              { v.w = l; } \
      } else { \
        v.x -= l * u4_##Q.x; v.y -= l * u4_##Q.y; v.z -= l * u4_##Q.z; v.w -= l * u4_##Q.w; \
      } \
      if (Q == qn) nv = (en == 0) ? v.x : (en == 1) ? v.y : (en == 2) ? v.z : v.w; \
      r##K##_##Q = v; \
    }
#define UPDK(K) \
    if (act##K) { \
      const int rr_ = tid + (K << 8); \
      float l = 0.0f, nv = 0.0f; \
      QSTEP(K,0) QSTEP(K,1) QSTEP(K,2) QSTEP(K,3) QSTEP(K,4) QSTEP(K,5) QSTEP(K,6) QSTEP(K,7) \
      if (j < 31) { \
        float av = fabsf(nv); \
        if (av > bval || (av == bval && rr_ < brow)) { bval = av; brow = rr_; } \
      } \
    }
    UPDK(0) UPDK(1) UPDK(2) UPDK(3)
#undef UPDK
#undef QSTEP

    if (j < 31) {
      #pragma unroll
      for (int mask = 32; mask; mask >>= 1) {
        float ov = __shfl_xor(bval, mask);
        int   orr = __shfl_xor(brow, mask);
        if (ov > bval || (ov == bval && orr < brow)) { bval = ov; brow = orr; }
      }
      if ((tid & 63) == 0) { redv[jn & 1][tid >> 6] = bval; redk[jn & 1][tid >> 6] = brow; }
    }
    __syncthreads();   // B2: updates done reading prow; redv visible for next step
  }

  // ---- writeback (all loaded rows, original slots) ----
#define STOREK(K) \
  if (ld##K) { \
    float* dst_ = A + (size_t)(c0 + tid + (K << 8)) * N + c0; \
    *(float4*)(dst_ +  0) = r##K##_0; \
    *(float4*)(dst_ +  4) = r##K##_1; \
    *(float4*)(dst_ +  8) = r##K##_2; \
    *(float4*)(dst_ + 12) = r##K##_3; \
    *(float4*)(dst_ + 16) = r##K##_4; \
    *(float4*)(dst_ + 20) = r##K##_5; \
    *(float4*)(dst_ + 24) = r##K##_6; \
    *(float4*)(dst_ + 28) = r##K##_7; \
  }
  STOREK(0) STOREK(1) STOREK(2) STOREK(3)
#undef STOREK

  // ---- emit permutation: rowsrc[i] = physical row (abs) holding virtual row i ----
  for (int i = tid; i < R; i += 256) rowsrc[m * 1024 + i] = (unsigned short)(c0 + Vv[i]);
  // ---- logsum: lane-parallel logs + shfl-reduce (wave 0) ----
  if (tid < 64) {
    double lg = 0.0;
    if (tid < 32) lg = log(fabs((double)ujjS[tid]));
    #pragma unroll
    for (int mask = 32; mask; mask >>= 1) lg += __shfl_xor(lg, mask);
    if (tid == 0) atomicAdd(&scores[m], lg);
  }
}

// ======================= permutation-gather + TRSM =======================
__global__ __launch_bounds__(256) void ptrsm_kernel(float* __restrict__ lu,
                                                    const unsigned short* __restrict__ rowsrc,
                                                    int c0, int ncs) {
  const int m  = blockIdx.x / ncs;
  const int cs = blockIdx.x % ncs;
  const int s0 = c0 + 32 + cs * 256;
  const int tid = threadIdx.x;
  const int col = s0 + tid;
  const bool ac = col < N;
  float* A = lu + (size_t)m * NN;
  const int R = N - c0;
  __shared__ int   rowAt[1024];     // content map over rows [c0, N)
  __shared__ float L11s[32][33];
  __shared__ int   dDst[48];
  __shared__ int   dSrc[48];
  __shared__ int   dcount;

  for (int r = tid; r < R; r += 256) rowAt[r] = (int)rowsrc[m * 1024 + r];
  if (tid == 0) dcount = 0;
  __syncthreads();
  for (int idx = tid; idx < 1024; idx += 256) {
    int i = idx >> 5, k = idx & 31;
    L11s[i][k] = A[(size_t)rowAt[i] * N + c0 + k];
  }
  // collect displaced A22 rows (dst receives content of src)
  for (int r = 32 + tid; r < R; r += 256) {
    if (rowAt[r] != c0 + r) {
      int i = atomicAdd(&dcount, 1);
      dDst[i] = c0 + r; dSrc[i] = rowAt[r];
    }
  }
  __syncthreads();
  const int nd = dcount;   // <= 32

  // ---- read phase (all loads before any store) ----
  float pay[32];
  #pragma unroll
  for (int i = 0; i < 32; ++i)
    if (i < nd && ac) pay[i] = A[(size_t)dSrc[i] * N + col];
  float u[32];
  #pragma unroll
  for (int i = 0; i < 32; ++i)
    if (ac) u[i] = A[(size_t)rowAt[i] * N + col];

  // ---- TRSM: u = L11^{-1} a12 (unit diag) ----
  #pragma unroll
  for (int i = 1; i < 32; ++i) {
    float a = u[i];
    #pragma unroll
    for (int k = 0; k < 32; ++k)
      if (k < i) a -= L11s[i][k] * u[k];
    u[i] = a;
  }

  // ---- write phase ----
  #pragma unroll
  for (int i = 0; i < 32; ++i)
    if (i < nd && ac) A[(size_t)dDst[i] * N + col] = pay[i];
  #pragma unroll
  for (int i = 0; i < 32; ++i)
    if (ac) A[(size_t)(c0 + i) * N + col] = u[i];
}

// ======================= trailing update: A22 -= L21 @ U12 (K=32) ================
__global__ __launch_bounds__(256) void update_kernel(float* __restrict__ lu,
                                                     const unsigned short* __restrict__ rowsrc,
                                                     int c0, int nrt, int ncs) {
  const int per = nrt * ncs;
  const int m  = blockIdx.x / per;
  const int t  = blockIdx.x % per;
  const int rt = t / ncs, cs = t % ncs;
  const int r0 = c0 + 32 + rt * 64;
  const int s0 = c0 + 32 + cs * 256;
  const int tid = threadIdx.x;
  float* A = lu + (size_t)m * NN;
  __shared__ float Lts[32][68];    // L21 tile transposed: [k][r]
  __shared__ float Us[32][260];    // U12 stripe: [k][c]
  for (int idx = tid; idx < 2048; idx += 256) {
    int r = idx >> 5, k = idx & 31;
    int rr = r0 + r;
    Lts[k][r] = (rr < N) ? A[(size_t)rowsrc[m * 1024 + rr - c0] * N + c0 + k] : 0.0f;
  }
  for (int idx = tid; idx < 8192; idx += 256) {
    int k = idx >> 8, c = idx & 255;
    Us[k][c] = (s0 + c < N) ? A[(size_t)(c0 + k) * N + s0 + c] : 0.0f;
  }
  __syncthreads();
  const int tx = tid & 63;    // col group: 4 cols
  const int ty = tid >> 6;    // row group: 16 rows (== wave id -> uniform a-reads)
  float4 acc[16];
  #pragma unroll
  for (int e = 0; e < 16; ++e) acc[e] = make_float4(0.f, 0.f, 0.f, 0.f);
  #pragma unroll 4
  for (int k = 0; k < 32; ++k) {
    float4 b  = *(const float4*)&Us[k][tx * 4];
    float4 a0 = *(const float4*)&Lts[k][ty * 16 + 0];
    float4 a1 = *(const float4*)&Lts[k][ty * 16 + 4];
    float4 a2 = *(const float4*)&Lts[k][ty * 16 + 8];
    float4 a3 = *(const float4*)&Lts[k][ty * 16 + 12];
    acc[0].x  += a0.x*b.x; acc[0].y  += a0.x*b.y; acc[0].z  += a0.x*b.z; acc[0].w  += a0.x*b.w;
    acc[1].x  += a0.y*b.x; acc[1].y  += a0.y*b.y; acc[1].z  += a0.y*b.z; acc[1].w  += a0.y*b.w;
    acc[2].x  += a0.z*b.x; acc[2].y  += a0.z*b.y; acc[2].z  += a0.z*b.z; acc[2].w  += a0.z*b.w;
    acc[3].x  += a0.w*b.x; acc[3].y  += a0.w*b.y; acc[3].z  += a0.w*b.z; acc[3].w  += a0.w*b.w;
    acc[4].x  += a1.x*b.x; acc[4].y  += a1.x*b.y; acc[4].z  += a1.x*b.z; acc[4].w  += a1.x*b.w;
    acc[5].x  += a1.y*b.x; acc[5].y  += a1.y*b.y; acc[5].z  += a1.y*b.z; acc[5].w  += a1.y*b.w;
    acc[6].x  += a1.z*b.x; acc[6].y  += a1.z*b.y; acc[6].z  += a1.z*b.z; acc[6].w  += a1.z*b.w;
    acc[7].x  += a1.w*b.x; acc[7].y  += a1.w*b.y; acc[7].z  += a1.w*b.z; acc[7].w  += a1.w*b.w;
    acc[8].x  += a2.x*b.x; acc[8].y  += a2.x*b.y; acc[8].z  += a2.x*b.z; acc[8].w  += a2.x*b.w;
    acc[9].x  += a2.y*b.x; acc[9].y  += a2.y*b.y; acc[9].z  += a2.y*b.z; acc[9].w  += a2.y*b.w;
    acc[10].x += a2.z*b.x; acc[10].y += a2.z*b.y; acc[10].z += a2.z*b.z; acc[10].w += a2.z*b.w;
    acc[11].x += a2.w*b.x; acc[11].y += a2.w*b.y; acc[11].z += a2.w*b.z; acc[11].w += a2.w*b.w;
    acc[12].x += a3.x*b.x; acc[12].y += a3.x*b.y; acc[12].z += a3.x*b.z; acc[12].w += a3.x*b.w;
    acc[13].x += a3.y*b.x; acc[13].y += a3.y*b.y; acc[13].z += a3.y*b.z; acc[13].w += a3.y*b.w;
    acc[14].x += a3.z*b.x; acc[14].y += a3.z*b.y; acc[14].z += a3.z*b.z; acc[14].w += a3.z*b.w;
    acc[15].x += a3.w*b.x; acc[15].y += a3.w*b.y; acc[15].z += a3.w*b.z; acc[15].w += a3.w*b.w;
  }
  const bool colok = (s0 + tx * 4) < N;
  #pragma unroll
  for (int e = 0; e < 16; ++e) {
    int r = r0 + ty * 16 + e;
    if (r < N && colok) {
      float4* p = (float4*)&A[(size_t)r * N + s0 + tx * 4];
      float4 v = *p;
      v.x -= acc[e].x; v.y -= acc[e].y; v.z -= acc[e].z; v.w -= acc[e].w;
      *p = v;
    }
  }
}

// ======================= gate + top-k + effective weights =======================
__global__ void select_kernel(const void* __restrict__ flagsraw, const double* __restrict__ scores,
                              const float* __restrict__ w1, const float* __restrict__ b1,
                              const float* __restrict__ w2, const float* __restrict__ b2,
                              int* __restrict__ topidx, float* __restrict__ misc,
                              float* __restrict__ out_tail) {
  if (threadIdx.x != 0 || blockIdx.x != 0) return;
  const unsigned char* fb = (const unsigned char*)flagsraw;
  bool nonbin = false, off4 = false;
  for (int i = 0; i < 16; ++i) {
    if (fb[i] > 1) nonbin = true;
    if ((i & 3) && fb[i]) off4 = true;
  }
  int f[16]; int nact = 0;
  for (int i = 0; i < 16; ++i) {
    int v;
    if (nonbin)      v = (((const float*)flagsraw)[i] != 0.0f);
    else if (off4)   v = (fb[i] != 0);
    else             v = (((const int*)flagsraw)[i] != 0);
    f[i] = v; nact += v;
  }
  int gate = (nact >= 4) ? 1 : 0;   // THRESH = 4
  double sc[16];
  for (int i = 0; i < 16; ++i) sc[i] = f[i] ? scores[i] : -1.0e300;
  bool used[16] = {};
  for (int k = 0; k < 8; ++k) {     // descending, ties -> lowest index (lax.top_k)
    int bi = -1; double bv = 0.0;
    for (int i = 0; i < 16; ++i)
      if (!used[i] && (bi < 0 || sc[i] > bv)) { bv = sc[i]; bi = i; }
    used[bi] = true;
    topidx[k] = bi;
  }
  for (int cC = 0; cC < 10; ++cC) {
    float s = 0.0f;
    for (int h = 0; h < 32; ++h) s += w2[h] * w1[h * 10 + cC];
    misc[cC] = s;
  }
  float be = 0.0f;
  for (int h = 0; h < 32; ++h) be += w2[h] * b1[h];
  be += b2[0];
  misc[10] = be;
  ((int*)misc)[12] = gate;
  *out_tail = gate ? 1.0f : 0.0f;
}

// ======================= build combined right-hand matrices M0..M2 =======================
__global__ __launch_bounds__(256) void build_m_kernel(const float* __restrict__ x,
                                                      const int* __restrict__ topidx,
                                                      const float* __restrict__ misc,
                                                      float* __restrict__ M) {
  int i = blockIdx.x * 256 + threadIdx.x;   // 262144 float4 positions
  const float4* T1 = (const float4*)(x + (size_t)topidx[1] * NN);
  const float4* T2 = (const float4*)(x + (size_t)topidx[2] * NN);
  const float4* T3 = (const float4*)(x + (size_t)topidx[3] * NN);
  float w0 = misc[0], w1_ = misc[1], w2_ = misc[2], w3_ = misc[3], w4_ = misc[4], w5_ = misc[5];
  float4 t1 = T1[i], t2 = T2[i], t3 = T3[i];
  float4 m0, m1, m2;
  m0.x = w0 * t1.x + w1_ * t2.x + w2_ * t3.x;
  m0.y = w0 * t1.y + w1_ * t2.y + w2_ * t3.y;
  m0.z = w0 * t1.z + w1_ * t2.z + w2_ * t3.z;
  m0.w = w0 * t1.w + w1_ * t2.w + w2_ * t3.w;
  m1.x = w3_ * t2.x + w4_ * t3.x;
  m1.y = w3_ * t2.y + w4_ * t3.y;
  m1.z = w3_ * t2.z + w4_ * t3.z;
  m1.w = w3_ * t2.w + w4_ * t3.w;
  m2.x = w5_ * t3.x;  m2.y = w5_ * t3.y;  m2.z = w5_ * t3.z;  m2.w = w5_ * t3.w;
  ((float4*)M)[i] = m0;
  ((float4*)(M + NN))[i] = m1;
  ((float4*)(M + 2 * (size_t)NN))[i] = m2;
}

// ======================= split-K final GEMM: P[chunk] = A_chunk @ B_chunk ==========
__global__ __launch_bounds__(256) void final_gemm_kernel(const float* __restrict__ x,
                                                         const float* __restrict__ M,
                                                         const int* __restrict__ topidx,
                                                         float* __restrict__ P) {
  const int chunk = blockIdx.x >> 8;   // 0..5
  const int t  = blockIdx.x & 255;
  const int tr = t >> 4, tc = t & 15;
  const int mi  = chunk >> 1;
  const int k0b = (chunk & 1) << 9;    // 0 or 512
  const float* A = x + (size_t)topidx[mi] * NN;
  const float* B = M + (size_t)mi * NN;
  __shared__ float As[32][68];   // A^T fragment: As[k][r], float4-aligned stride
  __shared__ float Bs[32][68];
  const int ty = threadIdx.x >> 4, tx = threadIdx.x & 15;
  float acc[4][4] = {};
  for (int k0 = k0b; k0 < k0b + 512; k0 += 32) {
    for (int idx = threadIdx.x; idx < 2048; idx += 256) {
      int r = idx >> 5, k = idx & 31;
      As[k][r] = A[(size_t)(tr * 64 + r) * N + k0 + k];
    }
    for (int idx = threadIdx.x; idx < 2048; idx += 256) {
      int k = idx >> 6, cc = idx & 63;
      Bs[k][cc] = B[(size_t)(k0 + k) * N + tc * 64 + cc];
    }
    __syncthreads();
    #pragma unroll 8
    for (int k = 0; k < 32; ++k) {
      float4 a = *(const float4*)&As[k][ty * 4];
      float4 b = *(const float4*)&Bs[k][tx * 4];
      acc[0][0] += a.x * b.x; acc[0][1] += a.x * b.y; acc[0][2] += a.x * b.z; acc[0][3] += a.x * b.w;
      acc[1][0] += a.y * b.x; acc[1][1] += a.y * b.y; acc[1][2] += a.y * b.z; acc[1][3] += a.y * b.w;
      acc[2][0] += a.z * b.x; acc[2][1] += a.z * b.y; acc[2][2] += a.z * b.z; acc[2][3] += a.z * b.w;
      acc[3][0] += a.w * b.x; acc[3][1] += a.w * b.y; acc[3][2] += a.w * b.z; acc[3][3] += a.w * b.w;
    }
    __syncthreads();
  }
  float* Pc = P + (size_t)chunk * NN;
  #pragma unroll
  for (int i = 0; i < 4; ++i) {
    size_t r = (size_t)(tr * 64 + ty * 4 + i);
    float4 v = make_float4(acc[i][0], acc[i][1], acc[i][2], acc[i][3]);
    *(float4*)&Pc[r * N + tc * 64 + tx * 4] = v;
  }
}

// ======================= reduce partials + preserve channels + bias ================
__global__ __launch_bounds__(256) void reduce_out_kernel(const float* __restrict__ x,
                                                         const float* __restrict__ P,
                                                         const int* __restrict__ topidx,
                                                         const float* __restrict__ misc,
                                                         float* __restrict__ out) {
  int i = blockIdx.x * 256 + threadIdx.x;   // 262144 float4 positions
  int gate = ((const int*)misc)[12];
  float4* o = (float4*)out;
  if (!gate) { o[i] = make_float4(0.f, 0.f, 0.f, 0.f); return; }
  float w6 = misc[6], w7 = misc[7], w8 = misc[8], w9 = misc[9], be = misc[10];
  float4 p0 = ((const float4*)(x + (size_t)topidx[4] * NN))[i];
  float4 p1 = ((const float4*)(x + (size_t)topidx[5] * NN))[i];
  float4 p2 = ((const float4*)(x + (size_t)topidx[6] * NN))[i];
  float4 p3 = ((const float4*)(x + (size_t)topidx[7] * NN))[i];
  float4 r;
  r.x = be + w6 * p0.x + w7 * p1.x + w8 * p2.x + w9 * p3.x;
  r.y = be + w6 * p0.y + w7 * p1.y + w8 * p2.y + w9 * p3.y;
  r.z = be + w6 * p0.z + w7 * p1.z + w8 * p2.z + w9 * p3.z;
  r.w = be + w6 * p0.w + w7 * p1.w + w8 * p2.w + w9 * p3.w;
  #pragma unroll
  for (int cN = 0; cN < 6; ++cN) {
    float4 q = ((const float4*)(P + (size_t)cN * NN))[i];
    r.x += q.x; r.y += q.y; r.z += q.z; r.w += q.w;
  }
  o[i] = r;
}

// ======================= host =======================
extern "C" void kernel_launch(void* const* d_in, const int* in_sizes, int n_in,
                              void* d_out, int out_size, void* d_ws, size_t ws_size,
                              hipStream_t stream) {
  const float* x  = (const float*)d_in[0];
  const void*  fl = d_in[1];
  const float* w1 = (const float*)d_in[2];
  const float* b1 = (const float*)d_in[3];
  const float* w2 = (const float*)d_in[4];
  const float* b2 = (const float*)d_in[5];
  float* out = (float*)d_out;

  char* ws = (char*)d_ws;
  float* LU = (float*)ws;                                // 64 MB (dead after LU phase)
  float* Mm = (float*)ws;                                // 12 MB, reuses LU space
  float* P  = (float*)(ws + (size_t)12 * 1024 * 1024);   // 24 MB partials, inside old LU
  size_t tail = (size_t)16 * NN * sizeof(float);         // 67,108,864
  double* scores = (double*)(ws + tail);                 // 16 doubles
  unsigned short* rowsrc = (unsigned short*)(ws + tail + 256);     // 16*1024 u16 = 32 KB
  int*    topidx = (int*)(ws + tail + 256 + 32768);      // 8 ints
  float*  misc   = (float*)(ws + tail + 256 + 32768 + 256); // weff[10], beff, gate

  init_kernel<<<1, 64, 0, stream>>>(scores);
  copy_kernel<<<16384, 256, 0, stream>>>((const float4*)x, (float4*)LU);

  for (int c0 = 0; c0 < N; c0 += 32) {
    panel_kernel<<<16, 256, 0, stream>>>(LU, rowsrc, scores, c0);
    int tcols = N - c0 - 32;
    if (tcols > 0) {
      int ncs = (tcols + 255) / 256;
      ptrsm_kernel<<<16 * ncs, 256, 0, stream>>>(LU, rowsrc, c0, ncs);
      int nrt = (tcols + 63) / 64;
      update_kernel<<<16 * nrt * ncs, 256, 0, stream>>>(LU, rowsrc, c0, nrt, ncs);
    }
  }

  select_kernel<<<1, 64, 0, stream>>>(fl, scores, w1, b1, w2, b2, topidx, misc, out + NN);
  build_m_kernel<<<1024, 256, 0, stream>>>(x, topidx, misc, Mm);
  final_gemm_kernel<<<1536, 256, 0, stream>>>(x, Mm, topidx, P);
  reduce_out_kernel<<<1024, 256, 0, stream>>>(x, P, topidx, misc, out);
}